// Round 4
// baseline (344.591 us; speedup 1.0000x reference)
//
#include <hip/hip_runtime.h>
#include <hip/hip_cooperative_groups.h>

namespace cg = cooperative_groups;

#define N_L 8
#define NTHREADS 256
#define NBLOCKS 1024   // 4 blocks/CU x 256 CUs, co-resident under __launch_bounds__(256,4)

// ---------------------------------------------------------------------------
// Phase 1 helper: resolve vertex row per reference scatter semantics and
// write softmax row (f32, 32B) to P. Binary search on LDS-staged fidx.
// ---------------------------------------------------------------------------
__device__ __forceinline__ void materialize_row(
    int v, const float* __restrict__ tr, const float* __restrict__ fx,
    const int* __restrict__ sf_lds, const int* __restrict__ fidx_g,
    int nF, bool useLds, float* __restrict__ P) {
  int lo = 0, hi = nF;
  if (useLds) {
    while (lo < hi) { int mid = (lo + hi) >> 1; if (sf_lds[mid] < v) lo = mid + 1; else hi = mid; }
  } else {
    while (lo < hi) { int mid = (lo + hi) >> 1; if (fidx_g[mid] < v) lo = mid + 1; else hi = mid; }
  }
  bool isFixed = useLds ? (lo < nF && sf_lds[lo] == v) : (lo < nF && fidx_g[lo] == v);
  const float* src = isFixed ? (fx + (size_t)lo * N_L) : (tr + (size_t)(v - lo) * N_L);
  float p[N_L];
  float4 a = *(const float4*)src;
  float4 b = *(const float4*)(src + 4);
  p[0] = a.x; p[1] = a.y; p[2] = a.z; p[3] = a.w;
  p[4] = b.x; p[5] = b.y; p[6] = b.z; p[7] = b.w;
  float m = p[0];
#pragma unroll
  for (int i = 1; i < N_L; ++i) m = fmaxf(m, p[i]);
  float s = 0.f;
#pragma unroll
  for (int i = 0; i < N_L; ++i) { p[i] = __expf(p[i] - m); s += p[i]; }
  float r = 1.0f / s;
  float4* dst = (float4*)(P + (size_t)v * N_L);
  dst[0] = make_float4(p[0] * r, p[1] * r, p[2] * r, p[3] * r);
  dst[1] = make_float4(p[4] * r, p[5] * r, p[6] * r, p[7] * r);
}

// ---------------------------------------------------------------------------
// Phase 2 helper: 8-lane-per-simplex gather. Lane e of each 8-lane group
// reads element e of each row -> one 32B coalesced segment per row.
// Returns this lane's partial energy (only the GLOBAL sum matters, so no
// per-simplex reduction is needed).
// Pair term per pair:   -(p.q)                        [+2/pair in cst]
// Triple term per tri:  -4*(d01+d02+d12) + (16/3)*T   [+8/tri in cst]
// ---------------------------------------------------------------------------
__device__ __forceinline__ float gather_local(
    int wave, int nWaves, int sub, int e,
    const int* __restrict__ s1, int nP,
    const int* __restrict__ s2, int nT,
    const float* __restrict__ P) {
  float local = 0.f;
  int nCp = (nP + 7) >> 3;
  for (int c = wave; c < nCp; c += nWaves) {
    int p = c * 8 + sub;
    if (p < nP) {
      int2 vv = ((const int2*)s1)[p];            // 8 lanes same addr -> 1 line
      float a = P[(size_t)vv.x * N_L + e];       // 8 rows/wave -> 8 lines
      float b = P[(size_t)vv.y * N_L + e];
      local -= a * b;
    }
  }
  int nCt = (nT + 7) >> 3;
  for (int c = wave; c < nCt; c += nWaves) {
    int t = c * 8 + sub;
    if (t < nT) {
      int v0 = s2[3 * t + 0];
      int v1 = s2[3 * t + 1];
      int v2 = s2[3 * t + 2];
      float a  = P[(size_t)v0 * N_L + e];
      float b  = P[(size_t)v1 * N_L + e];
      float cc = P[(size_t)v2 * N_L + e];
      local += -4.0f * (a * b + a * cc + b * cc) + (16.0f / 3.0f) * (a * b * cc);
    }
  }
  return local;
}

// Block (256 threads = 4 waves) sum reduction; result valid on thread 0.
__device__ __forceinline__ float block_reduce_sum(float v, float* smem) {
#pragma unroll
  for (int off = 32; off > 0; off >>= 1) v += __shfl_down(v, off, 64);
  int lane = threadIdx.x & 63;
  int wid  = threadIdx.x >> 6;
  if (lane == 0) smem[wid] = v;
  __syncthreads();
  if (threadIdx.x < 4) {
    v = smem[threadIdx.x];
    v += __shfl_down(v, 2, 64);
    v += __shfl_down(v, 1, 64);
  }
  return v;
}

// ---------------------------------------------------------------------------
// Cooperative single-dispatch kernel: materialize -> grid.sync -> gather ->
// grid.sync -> write out.
// ---------------------------------------------------------------------------
__global__ __launch_bounds__(NTHREADS, 4) void fused_energy(
    const float* __restrict__ tr, const float* __restrict__ fx,
    const int* __restrict__ fidx, int nF, int nV,
    const int* __restrict__ s1, int nP,
    const int* __restrict__ s2, int nT,
    float* __restrict__ P, double* __restrict__ acc,
    float* __restrict__ out, double cst) {
  __shared__ int sf[1024];
  __shared__ float red[4];
  cg::grid_group grid = cg::this_grid();

  const int tid  = blockIdx.x * NTHREADS + threadIdx.x;
  const int nThr = (int)gridDim.x * NTHREADS;

  // ---- Phase 1: materialize P ----
  if (tid == 0) acc[0] = 0.0;
  const bool useLds = (nF <= 1024);
  if (useLds) {
    for (int j = threadIdx.x; j < nF; j += NTHREADS) sf[j] = fidx[j];
    __syncthreads();
  }
  for (int v = tid; v < nV; v += nThr)
    materialize_row(v, tr, fx, sf, fidx, nF, useLds, P);

  grid.sync();

  // ---- Phase 2: gather energy ----
  const int wave   = tid >> 6;
  const int nWaves = nThr >> 6;
  const int sub    = (threadIdx.x & 63) >> 3;
  const int e      = threadIdx.x & 7;
  float local = gather_local(wave, nWaves, sub, e, s1, nP, s2, nT, P);
  float bsum = block_reduce_sum(local, red);
  if (threadIdx.x == 0) atomicAdd(acc, (double)bsum);

  grid.sync();
  if (tid == 0) out[0] = (float)(cst + atomicAdd(acc, 0.0));
}

// ---------------------------------------------------------------------------
// Non-cooperative fallback (if hipLaunchCooperativeKernel errors).
// ---------------------------------------------------------------------------
__global__ __launch_bounds__(256) void materialize_kernel(
    const float* __restrict__ tr, const float* __restrict__ fx,
    const int* __restrict__ fidx, int nF, int nV,
    float* __restrict__ P, double* __restrict__ acc) {
  __shared__ int sf[1024];
  const bool useLds = (nF <= 1024);
  if (useLds) {
    for (int j = threadIdx.x; j < nF; j += 256) sf[j] = fidx[j];
    __syncthreads();
  }
  int v = blockIdx.x * 256 + threadIdx.x;
  if (v == 0) acc[0] = 0.0;
  if (v < nV) materialize_row(v, tr, fx, sf, fidx, nF, useLds, P);
}

__global__ __launch_bounds__(256) void gather_kernel(
    const int* __restrict__ s1, int nP,
    const int* __restrict__ s2, int nT,
    const float* __restrict__ P, double* __restrict__ acc, int nWavesTotal) {
  __shared__ float red[4];
  const int tid  = blockIdx.x * 256 + threadIdx.x;
  const int wave = tid >> 6;
  const int sub  = (threadIdx.x & 63) >> 3;
  const int e    = threadIdx.x & 7;
  float local = gather_local(wave, nWavesTotal, sub, e, s1, nP, s2, nT, P);
  float bsum = block_reduce_sum(local, red);
  if (threadIdx.x == 0) atomicAdd(acc, (double)bsum);
}

__global__ void finalize(const double* __restrict__ acc,
                         float* __restrict__ out, double cst) {
  out[0] = (float)(cst + acc[0]);
}

// ---------------------------------------------------------------------------
// ws-too-small fallback: fully fused per-simplex softmax (round-0 path).
// ---------------------------------------------------------------------------
__global__ void init_acc(double* acc) { acc[0] = 0.0; }

__device__ __forceinline__ void load_P_row_fused(int v,
                                                 const float* __restrict__ tr,
                                                 const float* __restrict__ fx,
                                                 const int* __restrict__ fidx,
                                                 int nF, float p[N_L]) {
  int lo = 0, hi = nF;
  while (lo < hi) {
    int mid = (lo + hi) >> 1;
    if (fidx[mid] < v) lo = mid + 1; else hi = mid;
  }
  const float* src = (lo < nF && fidx[lo] == v) ? (fx + (size_t)lo * N_L)
                                                : (tr + (size_t)(v - lo) * N_L);
  float4 a = *(const float4*)src;
  float4 b = *(const float4*)(src + 4);
  p[0] = a.x; p[1] = a.y; p[2] = a.z; p[3] = a.w;
  p[4] = b.x; p[5] = b.y; p[6] = b.z; p[7] = b.w;
  float m = p[0];
#pragma unroll
  for (int i = 1; i < N_L; ++i) m = fmaxf(m, p[i]);
  float s = 0.f;
#pragma unroll
  for (int i = 0; i < N_L; ++i) { p[i] = __expf(p[i] - m); s += p[i]; }
  float r = 1.0f / s;
#pragma unroll
  for (int i = 0; i < N_L; ++i) p[i] *= r;
}

__global__ __launch_bounds__(256) void pair_kernel_fused(
    const int* __restrict__ simp, int n,
    const float* __restrict__ tr, const float* __restrict__ fx,
    const int* __restrict__ fidx, int nF, double* __restrict__ acc) {
  __shared__ float smem[4];
  int i = blockIdx.x * blockDim.x + threadIdx.x;
  float local = 0.f;
  if (i < n) {
    int2 vv = ((const int2*)simp)[i];
    float p[N_L], q[N_L];
    load_P_row_fused(vv.x, tr, fx, fidx, nF, p);
    load_P_row_fused(vv.y, tr, fx, fidx, nF, q);
    float d = 0.f;
#pragma unroll
    for (int t = 0; t < N_L; ++t) d += p[t] * q[t];
    local = -d;
  }
  float bsum = block_reduce_sum(local, smem);
  if (threadIdx.x == 0) atomicAdd(acc, (double)bsum);
}

__global__ __launch_bounds__(256) void triple_kernel_fused(
    const int* __restrict__ simp, int n,
    const float* __restrict__ tr, const float* __restrict__ fx,
    const int* __restrict__ fidx, int nF, double* __restrict__ acc) {
  __shared__ float smem[4];
  int i = blockIdx.x * blockDim.x + threadIdx.x;
  float local = 0.f;
  if (i < n) {
    int v0 = simp[3 * i + 0];
    int v1 = simp[3 * i + 1];
    int v2 = simp[3 * i + 2];
    float p[N_L], q[N_L], r[N_L];
    load_P_row_fused(v0, tr, fx, fidx, nF, p);
    load_P_row_fused(v1, tr, fx, fidx, nF, q);
    load_P_row_fused(v2, tr, fx, fidx, nF, r);
    float d01 = 0.f, d02 = 0.f, d12 = 0.f, t3 = 0.f;
#pragma unroll
    for (int t = 0; t < N_L; ++t) {
      d01 += p[t] * q[t];
      d02 += p[t] * r[t];
      d12 += q[t] * r[t];
      t3  += p[t] * q[t] * r[t];
    }
    local = -4.0f * (d01 + d02 + d12) + (16.0f / 3.0f) * t3;
  }
  float bsum = block_reduce_sum(local, smem);
  if (threadIdx.x == 0) atomicAdd(acc, (double)bsum);
}

extern "C" void kernel_launch(void* const* d_in, const int* in_sizes, int n_in,
                              void* d_out, int out_size, void* d_ws, size_t ws_size,
                              hipStream_t stream) {
  const float* tr   = (const float*)d_in[0];  // (N_V-N_FIXED, 8) f32
  const float* fx   = (const float*)d_in[1];  // (N_FIXED, 8) f32
  const int*   fidx = (const int*)d_in[2];    // (N_FIXED,) i32 (sorted)
  const int*   s1   = (const int*)d_in[3];    // (nP, 2) i32
  const int*   s2   = (const int*)d_in[4];    // (nT, 3) i32

  int nF = in_sizes[2];
  int nP = in_sizes[3] / 2;
  int nT = in_sizes[4] / 3;
  int nV = (in_sizes[0] + in_sizes[1]) / N_L;

  double* acc = (double*)d_ws;                // @0, 8B
  float*  P   = (float*)((char*)d_ws + 256);  // nV*8 f32, 32B rows
  float*  out = (float*)d_out;

  size_t need = 256 + (size_t)nV * N_L * sizeof(float);
  double cst = 2.0 * (double)nP + 8.0 * (double)nT;

  if (ws_size >= need) {
    void* args[] = {(void*)&tr, (void*)&fx, (void*)&fidx, (void*)&nF, (void*)&nV,
                    (void*)&s1, (void*)&nP, (void*)&s2, (void*)&nT,
                    (void*)&P, (void*)&acc, (void*)&out, (void*)&cst};
    hipError_t err = hipLaunchCooperativeKernel((const void*)fused_energy,
                                                dim3(NBLOCKS), dim3(NTHREADS),
                                                args, 0, stream);
    if (err != hipSuccess) {
      // Non-cooperative fallback: same phases as separate dispatches.
      materialize_kernel<<<(nV + 255) / 256, 256, 0, stream>>>(tr, fx, fidx, nF, nV, P, acc);
      int gBlocks = 1024;
      gather_kernel<<<gBlocks, 256, 0, stream>>>(s1, nP, s2, nT, P, acc, gBlocks * 4);
      finalize<<<1, 1, 0, stream>>>(acc, out, cst);
    }
  } else {
    init_acc<<<1, 1, 0, stream>>>(acc);
    pair_kernel_fused<<<(nP + 255) / 256, 256, 0, stream>>>(s1, nP, tr, fx, fidx, nF, acc);
    triple_kernel_fused<<<(nT + 255) / 256, 256, 0, stream>>>(s2, nT, tr, fx, fidx, nF, acc);
    finalize<<<1, 1, 0, stream>>>(acc, out, cst);
  }
}

// Round 5
// 133.283 us; speedup vs baseline: 2.5854x; 2.5854x over previous
//
#include <hip/hip_runtime.h>

#define N_L 8

// ---------------------------------------------------------------------------
// Block (256 threads = 4 waves) sum reduction; result valid on thread 0.
// ---------------------------------------------------------------------------
__device__ __forceinline__ float block_reduce_sum(float v, float* smem) {
#pragma unroll
  for (int off = 32; off > 0; off >>= 1) v += __shfl_down(v, off, 64);
  int lane = threadIdx.x & 63;
  int wid  = threadIdx.x >> 6;
  if (lane == 0) smem[wid] = v;
  __syncthreads();
  if (threadIdx.x < 4) {
    v = smem[threadIdx.x];
    v += __shfl_down(v, 2, 64);
    v += __shfl_down(v, 1, 64);
  }
  return v;
}

// ---------------------------------------------------------------------------
// Materialize softmax table P (nV x 8 f32, 32B rows) into workspace.
// Scatter semantics: full[fixed_indices]=fixed; full[sorted complement]=
// trainable in order -> binary search v in fidx (LDS-staged).
// Also zero-inits acc + done-counter for the gather kernel.
// ---------------------------------------------------------------------------
__global__ __launch_bounds__(256) void materialize_P(
    const float* __restrict__ tr, const float* __restrict__ fx,
    const int* __restrict__ fidx, int nF, int nV,
    float* __restrict__ P, double* __restrict__ acc,
    unsigned int* __restrict__ cnt) {
  __shared__ int sf[1024];
  const bool useLds = (nF <= 1024);
  if (useLds) {
    for (int j = threadIdx.x; j < nF; j += 256) sf[j] = fidx[j];
    __syncthreads();
  }
  int v = blockIdx.x * 256 + threadIdx.x;
  if (v == 0) { acc[0] = 0.0; cnt[0] = 0u; }
  if (v >= nV) return;

  const int* __restrict__ tab = useLds ? sf : fidx;
  int lo = 0, hi = nF;
  while (lo < hi) {
    int mid = (lo + hi) >> 1;
    if (tab[mid] < v) lo = mid + 1; else hi = mid;
  }
  const float* src = (lo < nF && tab[lo] == v) ? (fx + (size_t)lo * N_L)
                                               : (tr + (size_t)(v - lo) * N_L);
  float p[N_L];
  float4 a = *(const float4*)src;
  float4 b = *(const float4*)(src + 4);
  p[0] = a.x; p[1] = a.y; p[2] = a.z; p[3] = a.w;
  p[4] = b.x; p[5] = b.y; p[6] = b.z; p[7] = b.w;
  float m = p[0];
#pragma unroll
  for (int i = 1; i < N_L; ++i) m = fmaxf(m, p[i]);
  float s = 0.f;
#pragma unroll
  for (int i = 0; i < N_L; ++i) { p[i] = __expf(p[i] - m); s += p[i]; }
  float r = 1.0f / s;
  float4* dst = (float4*)(P + (size_t)v * N_L);
  dst[0] = make_float4(p[0] * r, p[1] * r, p[2] * r, p[3] * r);
  dst[1] = make_float4(p[4] * r, p[5] * r, p[6] * r, p[7] * r);
}

// ---------------------------------------------------------------------------
// Gather: thread-per-simplex (the proven R2 pattern) with G-way batching.
// All index loads issue first, then ALL row loads (independent, one waitcnt
// group), then compute. Tails are branch-free: clamp index, mask weight.
// Pair term:   -(p.q)                        [+2/pair in cst]
// Triple term: -4*(d01+d02+d12) + (16/3)*T   [+8/tri in cst]
// Finalize fused via done-counter.
// ---------------------------------------------------------------------------
#define BP 4   // pairs per thread
#define BT 2   // triples per thread

__global__ __launch_bounds__(256) void gather_energy(
    const int* __restrict__ s1, int nP,
    const int* __restrict__ s2, int nT,
    const float* __restrict__ P, double* __restrict__ acc,
    unsigned int* __restrict__ cnt, int pairBlocks, int totalBlocks,
    float* __restrict__ out, double cst) {
  __shared__ float smem[4];
  float local = 0.f;

  if ((int)blockIdx.x < pairBlocks) {
    const int2* __restrict__ s1v = (const int2*)s1;
    int base = blockIdx.x * (256 * BP) + threadIdx.x;
    int2  vv[BP];
    float w[BP];
#pragma unroll
    for (int u = 0; u < BP; ++u) {
      int i  = base + u * 256;
      int ii = min(i, nP - 1);
      w[u]   = (i < nP) ? 1.0f : 0.0f;
      vv[u]  = s1v[ii];
    }
    float4 a0[BP], a1[BP], b0[BP], b1[BP];
#pragma unroll
    for (int u = 0; u < BP; ++u) {
      const float4* A = (const float4*)(P + (size_t)vv[u].x * N_L);
      const float4* B = (const float4*)(P + (size_t)vv[u].y * N_L);
      a0[u] = A[0]; a1[u] = A[1];
      b0[u] = B[0]; b1[u] = B[1];
    }
#pragma unroll
    for (int u = 0; u < BP; ++u) {
      float d = a0[u].x * b0[u].x + a0[u].y * b0[u].y
              + a0[u].z * b0[u].z + a0[u].w * b0[u].w
              + a1[u].x * b1[u].x + a1[u].y * b1[u].y
              + a1[u].z * b1[u].z + a1[u].w * b1[u].w;
      local -= w[u] * d;
    }
  } else {
    int base = (blockIdx.x - pairBlocks) * (256 * BT) + threadIdx.x;
    int   v0[BT], v1[BT], v2[BT];
    float w[BT];
#pragma unroll
    for (int u = 0; u < BT; ++u) {
      int i  = base + u * 256;
      int ii = min(i, nT - 1);
      w[u]   = (i < nT) ? 1.0f : 0.0f;
      v0[u] = s2[3 * ii + 0];
      v1[u] = s2[3 * ii + 1];
      v2[u] = s2[3 * ii + 2];
    }
    float4 a0[BT], a1[BT], b0[BT], b1[BT], c0[BT], c1[BT];
#pragma unroll
    for (int u = 0; u < BT; ++u) {
      const float4* A = (const float4*)(P + (size_t)v0[u] * N_L);
      const float4* B = (const float4*)(P + (size_t)v1[u] * N_L);
      const float4* C = (const float4*)(P + (size_t)v2[u] * N_L);
      a0[u] = A[0]; a1[u] = A[1];
      b0[u] = B[0]; b1[u] = B[1];
      c0[u] = C[0]; c1[u] = C[1];
    }
#pragma unroll
    for (int u = 0; u < BT; ++u) {
      float pa[8] = {a0[u].x, a0[u].y, a0[u].z, a0[u].w, a1[u].x, a1[u].y, a1[u].z, a1[u].w};
      float pb[8] = {b0[u].x, b0[u].y, b0[u].z, b0[u].w, b1[u].x, b1[u].y, b1[u].z, b1[u].w};
      float pc[8] = {c0[u].x, c0[u].y, c0[u].z, c0[u].w, c1[u].x, c1[u].y, c1[u].z, c1[u].w};
      float d01 = 0.f, d02 = 0.f, d12 = 0.f, t3 = 0.f;
#pragma unroll
      for (int t = 0; t < N_L; ++t) {
        d01 += pa[t] * pb[t];
        d02 += pa[t] * pc[t];
        d12 += pb[t] * pc[t];
        t3  += pa[t] * pb[t] * pc[t];
      }
      local += w[u] * (-4.0f * (d01 + d02 + d12) + (16.0f / 3.0f) * t3);
    }
  }

  float bsum = block_reduce_sum(local, smem);
  if (threadIdx.x == 0) {
    atomicAdd(acc, (double)bsum);
    __threadfence();
    unsigned int done = atomicAdd(cnt, 1u);
    if (done == (unsigned int)(totalBlocks - 1)) {
      double total = atomicAdd(acc, 0.0);  // coherent read
      out[0] = (float)(cst + total);
    }
  }
}

// ---------------------------------------------------------------------------
// ws-too-small fallback: fully fused per-simplex softmax (round-0 path).
// ---------------------------------------------------------------------------
__global__ void init_acc(double* acc) { acc[0] = 0.0; }

__device__ __forceinline__ void load_P_row_fused(int v,
                                                 const float* __restrict__ tr,
                                                 const float* __restrict__ fx,
                                                 const int* __restrict__ fidx,
                                                 int nF, float p[N_L]) {
  int lo = 0, hi = nF;
  while (lo < hi) {
    int mid = (lo + hi) >> 1;
    if (fidx[mid] < v) lo = mid + 1; else hi = mid;
  }
  const float* src = (lo < nF && fidx[lo] == v) ? (fx + (size_t)lo * N_L)
                                                : (tr + (size_t)(v - lo) * N_L);
  float4 a = *(const float4*)src;
  float4 b = *(const float4*)(src + 4);
  p[0] = a.x; p[1] = a.y; p[2] = a.z; p[3] = a.w;
  p[4] = b.x; p[5] = b.y; p[6] = b.z; p[7] = b.w;
  float m = p[0];
#pragma unroll
  for (int i = 1; i < N_L; ++i) m = fmaxf(m, p[i]);
  float s = 0.f;
#pragma unroll
  for (int i = 0; i < N_L; ++i) { p[i] = __expf(p[i] - m); s += p[i]; }
  float r = 1.0f / s;
#pragma unroll
  for (int i = 0; i < N_L; ++i) p[i] *= r;
}

__global__ __launch_bounds__(256) void pair_kernel_fused(
    const int* __restrict__ simp, int n,
    const float* __restrict__ tr, const float* __restrict__ fx,
    const int* __restrict__ fidx, int nF, double* __restrict__ acc) {
  __shared__ float smem[4];
  int i = blockIdx.x * blockDim.x + threadIdx.x;
  float local = 0.f;
  if (i < n) {
    int2 vv = ((const int2*)simp)[i];
    float p[N_L], q[N_L];
    load_P_row_fused(vv.x, tr, fx, fidx, nF, p);
    load_P_row_fused(vv.y, tr, fx, fidx, nF, q);
    float d = 0.f;
#pragma unroll
    for (int t = 0; t < N_L; ++t) d += p[t] * q[t];
    local = -d;
  }
  float bsum = block_reduce_sum(local, smem);
  if (threadIdx.x == 0) atomicAdd(acc, (double)bsum);
}

__global__ __launch_bounds__(256) void triple_kernel_fused(
    const int* __restrict__ simp, int n,
    const float* __restrict__ tr, const float* __restrict__ fx,
    const int* __restrict__ fidx, int nF, double* __restrict__ acc) {
  __shared__ float smem[4];
  int i = blockIdx.x * blockDim.x + threadIdx.x;
  float local = 0.f;
  if (i < n) {
    int v0 = simp[3 * i + 0];
    int v1 = simp[3 * i + 1];
    int v2 = simp[3 * i + 2];
    float p[N_L], q[N_L], r[N_L];
    load_P_row_fused(v0, tr, fx, fidx, nF, p);
    load_P_row_fused(v1, tr, fx, fidx, nF, q);
    load_P_row_fused(v2, tr, fx, fidx, nF, r);
    float d01 = 0.f, d02 = 0.f, d12 = 0.f, t3 = 0.f;
#pragma unroll
    for (int t = 0; t < N_L; ++t) {
      d01 += p[t] * q[t];
      d02 += p[t] * r[t];
      d12 += q[t] * r[t];
      t3  += p[t] * q[t] * r[t];
    }
    local = -4.0f * (d01 + d02 + d12) + (16.0f / 3.0f) * t3;
  }
  float bsum = block_reduce_sum(local, smem);
  if (threadIdx.x == 0) atomicAdd(acc, (double)bsum);
}

__global__ void finalize(const double* __restrict__ acc,
                         float* __restrict__ out, double cst) {
  out[0] = (float)(cst + acc[0]);
}

extern "C" void kernel_launch(void* const* d_in, const int* in_sizes, int n_in,
                              void* d_out, int out_size, void* d_ws, size_t ws_size,
                              hipStream_t stream) {
  const float* tr   = (const float*)d_in[0];  // (N_V-N_FIXED, 8) f32
  const float* fx   = (const float*)d_in[1];  // (N_FIXED, 8) f32
  const int*   fidx = (const int*)d_in[2];    // (N_FIXED,) i32 (sorted)
  const int*   s1   = (const int*)d_in[3];    // (nP, 2) i32
  const int*   s2   = (const int*)d_in[4];    // (nT, 3) i32

  int nF = in_sizes[2];
  int nP = in_sizes[3] / 2;
  int nT = in_sizes[4] / 3;
  int nV = (in_sizes[0] + in_sizes[1]) / N_L;

  double*       acc = (double*)d_ws;                      // @0, 8B
  unsigned int* cnt = (unsigned int*)((char*)d_ws + 16);  // @16, 4B
  float*        P   = (float*)((char*)d_ws + 256);        // nV*8 f32
  float*        out = (float*)d_out;

  size_t need = 256 + (size_t)nV * N_L * sizeof(float);
  double cst = 2.0 * (double)nP + 8.0 * (double)nT;

  if (ws_size >= need) {
    materialize_P<<<(nV + 255) / 256, 256, 0, stream>>>(tr, fx, fidx, nF, nV, P, acc, cnt);
    int pairBlocks  = (nP + 256 * BP - 1) / (256 * BP);
    int triBlocks   = (nT + 256 * BT - 1) / (256 * BT);
    int totalBlocks = pairBlocks + triBlocks;
    gather_energy<<<totalBlocks, 256, 0, stream>>>(
        s1, nP, s2, nT, P, acc, cnt, pairBlocks, totalBlocks, out, cst);
  } else {
    init_acc<<<1, 1, 0, stream>>>(acc);
    pair_kernel_fused<<<(nP + 255) / 256, 256, 0, stream>>>(s1, nP, tr, fx, fidx, nF, acc);
    triple_kernel_fused<<<(nT + 255) / 256, 256, 0, stream>>>(s2, nT, tr, fx, fidx, nF, acc);
    finalize<<<1, 1, 0, stream>>>(acc, out, cst);
  }
}